// Round 1
// baseline (308.839 us; speedup 1.0000x reference)
//
#include <hip/hip_runtime.h>
#include <stdint.h>

typedef unsigned short u16;
typedef __bf16 bf16x8 __attribute__((ext_vector_type(8)));
typedef float f32x4 __attribute__((ext_vector_type(4)));
typedef unsigned int u32;

// ---------------------------------------------------------------------------
// Layout constants (elements = u16 units) of the weight "A-image" in d_ws.
//   Layer0 : K=128 (96 enc + bias@96 + pad), 128 rows -> 16 kchunks*128*8 = 16384 elems
//   Hidden l (1..7): K=256 (128 hid + 96 enc + bias@224 + pad)           = 32768 elems
//   Out    : K=256, 16 rows (4 real)                                     =  4096 elems
// Granule layout: elem[((kchunk*R + row)*8) + (k&7)]  (16B granules, A-frag native)
// ---------------------------------------------------------------------------
#define IMG_L0 0
#define IMG_H(l) (16384 + ((l)-1) * 32768)
#define IMG_OUT 245760
#define IMG_TOTAL 249856

// k-position permutation for the hidden-feature section (see C/D layout of
// mfma_f32_16x16x32: row = 4*(lane>>4)+reg, col = lane&15).  sigma^-1:
__device__ inline int sinv(int q) {           // q = k-position 0..127 -> C row
    int s = q >> 5, gg = (q >> 3) & 3, u = (q >> 2) & 1, t = q & 3;
    return 16 * (2 * s + u) + 4 * gg + t;
}
// encoding k-position -> reference enc feature index (coord*32 + trig*16 + freq)
__device__ inline int encmap(int q) {         // q in 0..95
    int c = q >> 5, gg = (q >> 3) & 3, u = (q >> 2) & 1, t = q & 3;
    int trig = gg >> 1, freq = 8 * (gg & 1) + 4 * u + t;
    return c * 32 + trig * 16 + freq;
}
__device__ inline u16 b16rne(float v) {
    u32 u = __builtin_bit_cast(u32, v);
    u += 0x7FFFu + ((u >> 16) & 1u);          // round-to-nearest-even
    return (u16)(u >> 16);
}

// ---------------------------------------------------------------------------
// Prep kernel: build bf16 A-image (sigma-permuted cols, bias folded at k=96/224,
// zero padding).  One thread per image element; rewrites everything each call
// (d_ws is re-poisoned before every timed launch).
// ---------------------------------------------------------------------------
__global__ void nf_prep(const float* __restrict__ W0, const float* __restrict__ b0,
                        const float* __restrict__ Wh, const float* __restrict__ bh,
                        const float* __restrict__ Wl, const float* __restrict__ bl,
                        u16* __restrict__ img) {
    int idx = blockIdx.x * 256 + threadIdx.x;
    if (idx >= IMG_TOTAL) return;
    int kpos, i, R, base;
    float v;
    if (idx < 16384) {                                    // layer 0
        kpos = idx >> 7; i = idx & 127; R = 128; base = IMG_L0;
        v = (kpos < 96) ? W0[encmap(kpos) * 128 + i]
          : (kpos == 96) ? b0[i] : 0.f;
    } else if (idx < IMG_OUT) {                           // hidden 1..7
        int r = idx - 16384; int l = r >> 15; int rr = r & 32767;
        kpos = rr >> 7; i = rr & 127; R = 128; base = 16384 + l * 32768;
        const float* W = Wh + l * 224 * 128;
        v = (kpos < 128) ? W[sinv(kpos) * 128 + i]
          : (kpos < 224) ? W[(128 + encmap(kpos - 128)) * 128 + i]
          : (kpos == 224) ? bh[l * 128 + i] : 0.f;
    } else {                                              // output layer
        int r = idx - IMG_OUT; kpos = r >> 4; i = r & 15; R = 16; base = IMG_OUT;
        v = 0.f;
        if (i < 4) {
            v = (kpos < 128) ? Wl[sinv(kpos) * 4 + i]
              : (kpos < 224) ? Wl[(128 + encmap(kpos - 128)) * 4 + i]
              : (kpos == 224) ? bl[i] : 0.f;
        }
    }
    img[base + (((kpos >> 3) * R + i) << 3) + (kpos & 7)] = b16rne(v);
}

// ---------------------------------------------------------------------------
// Main kernel helpers
// ---------------------------------------------------------------------------
__device__ inline f32x4 MF(bf16x8 a, bf16x8 b, f32x4 c) {
    return __builtin_amdgcn_mfma_f32_16x16x32_bf16(a, b, c, 0, 0, 0);
}
__device__ inline bf16x8 fr4(const u32 (&p)[4]) {
    union { u32 u[4]; bf16x8 v; } x;
    x.u[0] = p[0]; x.u[1] = p[1]; x.u[2] = p[2]; x.u[3] = p[3];
    return x.v;
}
__device__ inline bf16x8 frCB(u32 c0) {
    union { u32 u[4]; bf16x8 v; } x;
    x.u[0] = c0; x.u[1] = 0; x.u[2] = 0; x.u[3] = 0;
    return x.v;
}
__device__ inline bf16x8 ldA(const u16* base, int gi) {   // ds_read_b128
    union { uint4 q; bf16x8 v; } x;
    x.q = *(const uint4*)(base + (gi << 3));
    return x.v;
}
// pack two fp32 -> bf16x2 (round-half-away, 1 add each + v_perm)
__device__ inline u32 pkbf(float a, float b) {
    u32 ua = __builtin_bit_cast(u32, a) + 0x8000u;
    u32 ub = __builtin_bit_cast(u32, b) + 0x8000u;
    return __builtin_amdgcn_perm(ub, ua, 0x07060302u);
}
// async global->LDS stage, 16B/lane, chunks of 1KB round-robined over 8 waves
__device__ inline void stageA(const u16* gsrc, u16* ldst, int bytes, int wave, int lane) {
    const char* gs = (const char*)gsrc + lane * 16;
    char* ls = (char*)ldst;
    for (int c = wave * 1024; c < bytes; c += 8192)
        __builtin_amdgcn_global_load_lds(
            (const __attribute__((address_space(1))) void*)(gs + c),
            (__attribute__((address_space(3))) void*)(ls + c), 16, 0, 0);
}
__device__ inline void zeroacc(f32x4 (&acc)[8][2]) {
#pragma unroll
    for (int T = 0; T < 8; T++) {
        acc[T][0] = f32x4{0.f, 0.f, 0.f, 0.f};
        acc[T][1] = f32x4{0.f, 0.f, 0.f, 0.f};
    }
}
// ReLU + pack accumulators into next-layer B fragments (pure in-register)
__device__ inline void buildH(const f32x4 (&acc)[8][2], u32 (&H)[2][4][4]) {
#pragma unroll
    for (int n = 0; n < 2; n++)
#pragma unroll
        for (int s = 0; s < 4; s++) {
            f32x4 a = acc[2 * s][n], b = acc[2 * s + 1][n];
            float a0 = fmaxf(a[0], 0.f), a1 = fmaxf(a[1], 0.f);
            float a2 = fmaxf(a[2], 0.f), a3 = fmaxf(a[3], 0.f);
            float c0 = fmaxf(b[0], 0.f), c1 = fmaxf(b[1], 0.f);
            float c2 = fmaxf(b[2], 0.f), c3 = fmaxf(b[3], 0.f);
            H[n][s][0] = pkbf(a0, a1); H[n][s][1] = pkbf(a2, a3);
            H[n][s][2] = pkbf(c0, c1); H[n][s][3] = pkbf(c2, c3);
        }
}
// layer-0 half (2 ksteps over 8 feature tiles)
template <int HALF>
__device__ inline void compute_l0(const u16* A, int g, int m, f32x4 (&acc)[8][2],
                                  const u32 (&E)[2][3][4], u32 CB0) {
#pragma unroll
    for (int sr = 0; sr < 2; sr++) {
        const int s = HALF * 2 + sr;
        bf16x8 B0, B1;
        if (s < 3) { B0 = fr4(E[0][s]); B1 = fr4(E[1][s]); }
        else       { B0 = frCB(CB0);    B1 = B0; }
#pragma unroll
        for (int T = 0; T < 8; T++) {
            bf16x8 a = ldA(A, (4 * sr + g) * 128 + 16 * T + m);
            acc[T][0] = MF(a, B0, acc[T][0]);
            acc[T][1] = MF(a, B1, acc[T][1]);
        }
    }
}
// hidden half: HALF=0 -> ksteps 0..3 (hidden feats, H frags);
//              HALF=1 -> ksteps 4..7 (enc + bias frags)
template <int HALF>
__device__ inline void compute_half(const u16* A, int g, int m, f32x4 (&acc)[8][2],
                                    const u32 (&H)[2][4][4], const u32 (&E)[2][3][4],
                                    u32 CB0) {
#pragma unroll
    for (int sr = 0; sr < 4; sr++) {
        const int s = HALF * 4 + sr;
        bf16x8 B0, B1;
        if (s < 4)      { B0 = fr4(H[0][s]);     B1 = fr4(H[1][s]); }
        else if (s < 7) { B0 = fr4(E[0][s - 4]); B1 = fr4(E[1][s - 4]); }
        else            { B0 = frCB(CB0);        B1 = B0; }
#pragma unroll
        for (int T = 0; T < 8; T++) {
            bf16x8 a = ldA(A, (4 * sr + g) * 128 + 16 * T + m);
            acc[T][0] = MF(a, B0, acc[T][0]);
            acc[T][1] = MF(a, B1, acc[T][1]);
        }
    }
}

// ---------------------------------------------------------------------------
// Main fused-MLP kernel.  Block = 512 threads = 8 waves, 256 points/block.
// Wave handles 32 points (2 n-tiles of 16), all 128 features (8 m-tiles).
// Activations never leave registers; weights half-layer double-buffered in LDS.
// ---------------------------------------------------------------------------
__global__ __launch_bounds__(512, 2) void nf_main(const float* __restrict__ qp,
                                                  const u16* __restrict__ img,
                                                  float* __restrict__ out) {
    __shared__ alignas(16) u16 lds[2][16384];   // 2 x 32 KB slabs
    const int tid = threadIdx.x, wave = tid >> 6, lane = tid & 63;
    const int m = lane & 15, g = lane >> 4;
    const int pbase = blockIdx.x * 256 + wave * 32;

    // stage layer-0 slab A (kchunks 0..7) into slot 0
    stageA(img + IMG_L0, &lds[0][0], 16384, wave, lane);

    // ---- frequency encoding fragments (computed once, reused all layers) ----
    float xs[2][3];
#pragma unroll
    for (int c = 0; c < 3; c++) {
        xs[0][c] = qp[(pbase + m) * 3 + c];
        xs[1][c] = qp[(pbase + 16 + m) * 3 + c];
    }
    u32 E[2][3][4];
    const float sc0 = (g & 1) ? 128.0f : 0.5f;   // 2^(freq-1), freq base 8*(g&1)
    const bool iscos = (g & 2);
#pragma unroll
    for (int n = 0; n < 2; n++)
#pragma unroll
        for (int c = 0; c < 3; c++) {
            float r = xs[n][c] * sc0;            // revolutions: x * 2^(f-1) (exact)
            float v[8];
#pragma unroll
            for (int t = 0; t < 8; t++) {
                float fr = __builtin_amdgcn_fractf(r);
                v[t] = iscos ? __builtin_amdgcn_cosf(fr) : __builtin_amdgcn_sinf(fr);
                r = r * 2.0f;
            }
            E[n][c][0] = pkbf(v[0], v[1]); E[n][c][1] = pkbf(v[2], v[3]);
            E[n][c][2] = pkbf(v[4], v[5]); E[n][c][3] = pkbf(v[6], v[7]);
        }
    const u32 CB0 = (g == 0) ? 0x00003F80u : 0u;   // bf16(1.0) at k-offset 0
    f32x4 acc[8][2];
    u32 H[2][4][4];
    zeroacc(acc);

    __syncthreads();                                        // L0a ready
    stageA(img + IMG_L0 + 8192, &lds[1][0], 16384, wave, lane);  // L0b
    compute_l0<0>(&lds[0][0], g, m, acc, E, CB0);
    __syncthreads();                                        // L0b ready, slot0 free
    stageA(img + IMG_H(1), &lds[0][0], 32768, wave, lane);  // H1 slab A
    compute_l0<1>(&lds[1][0], g, m, acc, E, CB0);
    buildH(acc, H);
    __syncthreads();

#pragma unroll 1
    for (int l = 1; l < 8; l++) {
        const int ibase = IMG_H(l);
        stageA(img + ibase + 16384, &lds[1][0], 32768, wave, lane);  // slab B
        zeroacc(acc);
        compute_half<0>(&lds[0][0], g, m, acc, H, E, CB0);
        __syncthreads();
        const u16* nsrc = (l < 7) ? (img + ibase + 32768) : (img + IMG_OUT);
        stageA(nsrc, &lds[0][0], (l < 7) ? 32768 : 8192, wave, lane);
        compute_half<1>(&lds[1][0], g, m, acc, H, E, CB0);
        buildH(acc, H);
        __syncthreads();
    }

    // ---- output layer: 16-row tile (4 real outputs), K=256 from slot 0 ----
    f32x4 o0 = {0.f, 0.f, 0.f, 0.f}, o1 = {0.f, 0.f, 0.f, 0.f};
#pragma unroll
    for (int s = 0; s < 8; s++) {
        bf16x8 B0, B1;
        if (s < 4)      { B0 = fr4(H[0][s]);     B1 = fr4(H[1][s]); }
        else if (s < 7) { B0 = fr4(E[0][s - 4]); B1 = fr4(E[1][s - 4]); }
        else            { B0 = frCB(CB0);        B1 = B0; }
        bf16x8 a = ldA(&lds[0][0], (4 * s + g) * 16 + m);
        o0 = MF(a, B0, o0);
        o1 = MF(a, B1, o1);
    }
    if (g == 0) {   // rows 0..3 live in lanes 0..15, regs 0..3 (col = point)
        *(f32x4*)(out + 4 * (pbase + m))      = o0;
        *(f32x4*)(out + 4 * (pbase + 16 + m)) = o1;
    }
}

// ---------------------------------------------------------------------------
extern "C" void kernel_launch(void* const* d_in, const int* in_sizes, int n_in,
                              void* d_out, int out_size, void* d_ws, size_t ws_size,
                              hipStream_t stream) {
    const float* qp = (const float*)d_in[0];
    const float* W0 = (const float*)d_in[1];
    const float* b0 = (const float*)d_in[2];
    const float* Wh = (const float*)d_in[3];
    const float* bh = (const float*)d_in[4];
    const float* Wl = (const float*)d_in[5];
    const float* bl = (const float*)d_in[6];
    float* out = (float*)d_out;
    u16* img = (u16*)d_ws;   // 499,712 B needed

    nf_prep<<<976, 256, 0, stream>>>(W0, b0, Wh, bh, Wl, bl, img);
    nf_main<<<2048, 512, 0, stream>>>(qp, img, out);
}

// Round 2
// 267.061 us; speedup vs baseline: 1.1564x; 1.1564x over previous
//
#include <hip/hip_runtime.h>
#include <stdint.h>

typedef unsigned short u16;
typedef __bf16 bf16x8 __attribute__((ext_vector_type(8)));
typedef float f32x4 __attribute__((ext_vector_type(4)));
typedef unsigned int u32;

#define NT 4   // n-tiles (16 points each) per wave -> 64 points/wave

// ---------------------------------------------------------------------------
// Weight "A-image" layout in d_ws (elements = u16):
//   Layer0 : K=128 (96 enc + bias@96 + pad), 128 rows  -> 16384 elems
//   Hidden l (1..7): K=256 (128 hid + 96 enc + bias@224 + pad) -> 32768 elems
//   Out    : K=256, 16 rows (4 real)                    -> 4096 elems
// Granule: elem[((kchunk*R + row)*8) + (k&7)]  (16B granules, A-frag native)
// ---------------------------------------------------------------------------
#define IMG_L0 0
#define IMG_H(l) (16384 + ((l)-1) * 32768)
#define IMG_OUT 245760
#define IMG_TOTAL 249856

// k-position permutation for hidden-feature section (C/D layout of
// mfma_f32_16x16x32: row = 4*(lane>>4)+reg, col = lane&15).  sigma^-1:
__device__ inline int sinv(int q) {
    int s = q >> 5, gg = (q >> 3) & 3, u = (q >> 2) & 1, t = q & 3;
    return 16 * (2 * s + u) + 4 * gg + t;
}
// encoding k-position -> reference enc feature index
__device__ inline int encmap(int q) {
    int c = q >> 5, gg = (q >> 3) & 3, u = (q >> 2) & 1, t = q & 3;
    int trig = gg >> 1, freq = 8 * (gg & 1) + 4 * u + t;
    return c * 32 + trig * 16 + freq;
}
__device__ inline u16 b16rne(float v) {
    u32 u = __builtin_bit_cast(u32, v);
    u += 0x7FFFu + ((u >> 16) & 1u);
    return (u16)(u >> 16);
}

// ---------------------------------------------------------------------------
// Prep kernel: build bf16 A-image (sigma-permuted cols, bias folded, padded).
// ---------------------------------------------------------------------------
__global__ void nf_prep(const float* __restrict__ W0, const float* __restrict__ b0,
                        const float* __restrict__ Wh, const float* __restrict__ bh,
                        const float* __restrict__ Wl, const float* __restrict__ bl,
                        u16* __restrict__ img) {
    int idx = blockIdx.x * 256 + threadIdx.x;
    if (idx >= IMG_TOTAL) return;
    int kpos, i, R, base;
    float v;
    if (idx < 16384) {                                    // layer 0
        kpos = idx >> 7; i = idx & 127; R = 128; base = IMG_L0;
        v = (kpos < 96) ? W0[encmap(kpos) * 128 + i]
          : (kpos == 96) ? b0[i] : 0.f;
    } else if (idx < IMG_OUT) {                           // hidden 1..7
        int r = idx - 16384; int l = r >> 15; int rr = r & 32767;
        kpos = rr >> 7; i = rr & 127; R = 128; base = 16384 + l * 32768;
        const float* W = Wh + l * 224 * 128;
        v = (kpos < 128) ? W[sinv(kpos) * 128 + i]
          : (kpos < 224) ? W[(128 + encmap(kpos - 128)) * 128 + i]
          : (kpos == 224) ? bh[l * 128 + i] : 0.f;
    } else {                                              // output layer
        int r = idx - IMG_OUT; kpos = r >> 4; i = r & 15; R = 16; base = IMG_OUT;
        v = 0.f;
        if (i < 4) {
            v = (kpos < 128) ? Wl[sinv(kpos) * 4 + i]
              : (kpos < 224) ? Wl[(128 + encmap(kpos - 128)) * 4 + i]
              : (kpos == 224) ? bl[i] : 0.f;
        }
    }
    img[base + (((kpos >> 3) * R + i) << 3) + (kpos & 7)] = b16rne(v);
}

// ---------------------------------------------------------------------------
// Main kernel helpers
// ---------------------------------------------------------------------------
__device__ inline f32x4 MF(bf16x8 a, bf16x8 b, f32x4 c) {
    return __builtin_amdgcn_mfma_f32_16x16x32_bf16(a, b, c, 0, 0, 0);
}
__device__ inline bf16x8 fr4(const u32 (&p)[4]) {
    union { u32 u[4]; bf16x8 v; } x;
    x.u[0] = p[0]; x.u[1] = p[1]; x.u[2] = p[2]; x.u[3] = p[3];
    return x.v;
}
__device__ inline bf16x8 frCB(u32 c0) {
    union { u32 u[4]; bf16x8 v; } x;
    x.u[0] = c0; x.u[1] = 0; x.u[2] = 0; x.u[3] = 0;
    return x.v;
}
__device__ inline bf16x8 ldA(const u16* base, int gi) {   // ds_read_b128
    union { uint4 q; bf16x8 v; } x;
    x.q = *(const uint4*)(base + (gi << 3));
    return x.v;
}
__device__ inline u32 pkbf(float a, float b) {
    u32 ua = __builtin_bit_cast(u32, a) + 0x8000u;
    u32 ub = __builtin_bit_cast(u32, b) + 0x8000u;
    return __builtin_amdgcn_perm(ub, ua, 0x07060302u);
}
// frequency-encoding B fragment for one (point, coord), lane's (g) freq/trig slot
__device__ inline bf16x8 encFrag(float x, float sc0, bool iscos) {
    float r = x * sc0;                         // revolutions (exact pow2 scale)
    float v[8];
#pragma unroll
    for (int t = 0; t < 8; t++) {
        float fr = __builtin_amdgcn_fractf(r);
        v[t] = iscos ? __builtin_amdgcn_cosf(fr) : __builtin_amdgcn_sinf(fr);
        r = r * 2.0f;
    }
    union { u32 u[4]; bf16x8 v; } o;
    o.u[0] = pkbf(v[0], v[1]); o.u[1] = pkbf(v[2], v[3]);
    o.u[2] = pkbf(v[4], v[5]); o.u[3] = pkbf(v[6], v[7]);
    return o.v;
}
// async global->LDS stage, 16B/lane, 1KB chunks round-robined over 4 waves
__device__ inline void stageA(const u16* gsrc, u16* ldst, int bytes, int wave, int lane) {
    const char* gs = (const char*)gsrc + lane * 16;
    char* ls = (char*)ldst;
    for (int c = wave * 1024; c < bytes; c += 4096)
        __builtin_amdgcn_global_load_lds(
            (const __attribute__((address_space(1))) void*)(gs + c),
            (__attribute__((address_space(3))) void*)(ls + c), 16, 0, 0);
}
__device__ inline void zeroacc(f32x4 (&acc)[8][NT]) {
#pragma unroll
    for (int T = 0; T < 8; T++)
#pragma unroll
        for (int n = 0; n < NT; n++)
            acc[T][n] = f32x4{0.f, 0.f, 0.f, 0.f};
}
// ReLU + pack accumulators into next-layer B fragments (pure in-register)
__device__ inline void buildH(const f32x4 (&acc)[8][NT], u32 (&H)[NT][4][4]) {
#pragma unroll
    for (int n = 0; n < NT; n++)
#pragma unroll
        for (int s = 0; s < 4; s++) {
            f32x4 a = acc[2 * s][n], b = acc[2 * s + 1][n];
            H[n][s][0] = pkbf(fmaxf(a[0], 0.f), fmaxf(a[1], 0.f));
            H[n][s][1] = pkbf(fmaxf(a[2], 0.f), fmaxf(a[3], 0.f));
            H[n][s][2] = pkbf(fmaxf(b[0], 0.f), fmaxf(b[1], 0.f));
            H[n][s][3] = pkbf(fmaxf(b[2], 0.f), fmaxf(b[3], 0.f));
        }
}
// layer-0 half: ksteps s = HALF*2 + {0,1};  s<3 -> enc, s==3 -> bias
template <int HALF>
__device__ inline void computeL0(const u16* A, int g, int m, f32x4 (&acc)[8][NT],
                                 const float (&xs)[NT][3], float sc0, bool iscos,
                                 u32 CB0) {
#pragma unroll
    for (int sr = 0; sr < 2; sr++) {
        const int s = HALF * 2 + sr;
        bf16x8 B[NT];
        if (s < 3) {
#pragma unroll
            for (int n = 0; n < NT; n++) B[n] = encFrag(xs[n][s], sc0, iscos);
        } else {
            bf16x8 cb = frCB(CB0);
#pragma unroll
            for (int n = 0; n < NT; n++) B[n] = cb;
        }
#pragma unroll
        for (int T = 0; T < 8; T++) {
            bf16x8 a = ldA(A, (4 * sr + g) * 128 + 16 * T + m);
#pragma unroll
            for (int n = 0; n < NT; n++) acc[T][n] = MF(a, B[n], acc[T][n]);
        }
    }
}
// hidden half 0: ksteps 0..3, B from H fragments
__device__ inline void computeHalf0(const u16* A, int g, int m, f32x4 (&acc)[8][NT],
                                    const u32 (&H)[NT][4][4]) {
#pragma unroll
    for (int sr = 0; sr < 4; sr++) {
        bf16x8 B[NT];
#pragma unroll
        for (int n = 0; n < NT; n++) B[n] = fr4(H[n][sr]);
#pragma unroll
        for (int T = 0; T < 8; T++) {
            bf16x8 a = ldA(A, (4 * sr + g) * 128 + 16 * T + m);
#pragma unroll
            for (int n = 0; n < NT; n++) acc[T][n] = MF(a, B[n], acc[T][n]);
        }
    }
}
// hidden half 1: ksteps 4..7, B = enc (recomputed) then bias
__device__ inline void computeHalf1(const u16* A, int g, int m, f32x4 (&acc)[8][NT],
                                    const float (&xs)[NT][3], float sc0, bool iscos,
                                    u32 CB0) {
#pragma unroll
    for (int sr = 0; sr < 4; sr++) {
        bf16x8 B[NT];
        if (sr < 3) {
#pragma unroll
            for (int n = 0; n < NT; n++) B[n] = encFrag(xs[n][sr], sc0, iscos);
        } else {
            bf16x8 cb = frCB(CB0);
#pragma unroll
            for (int n = 0; n < NT; n++) B[n] = cb;
        }
#pragma unroll
        for (int T = 0; T < 8; T++) {
            bf16x8 a = ldA(A, (4 * sr + g) * 128 + 16 * T + m);
#pragma unroll
            for (int n = 0; n < NT; n++) acc[T][n] = MF(a, B[n], acc[T][n]);
        }
    }
}

// ---------------------------------------------------------------------------
// Main fused-MLP kernel.  Block = 256 threads = 4 waves, 256 points/block.
// Wave handles 64 points (4 n-tiles), all 128 features (8 m-tiles).
// Activations live in registers; weights half-layer double-buffered in LDS.
// Encoding fragments recomputed per layer (trades VALU-trans for 48 VGPRs).
// ---------------------------------------------------------------------------
__global__ __launch_bounds__(256, 2) void nf_main(const float* __restrict__ qp,
                                                  const u16* __restrict__ img,
                                                  float* __restrict__ out) {
    __shared__ alignas(16) u16 lds[2][16384];   // 2 x 32 KB slabs
    const int tid = threadIdx.x, wave = tid >> 6, lane = tid & 63;
    const int m = lane & 15, g = lane >> 4;
    const int pbase = blockIdx.x * 256 + wave * 64;

    stageA(img + IMG_L0, &lds[0][0], 16384, wave, lane);   // L0 slab A

    float xs[NT][3];
#pragma unroll
    for (int n = 0; n < NT; n++)
#pragma unroll
        for (int c = 0; c < 3; c++)
            xs[n][c] = qp[(pbase + n * 16 + m) * 3 + c];

    const float sc0 = (g & 1) ? 128.0f : 0.5f;   // 2^(freq_base-1)
    const bool iscos = (g & 2);
    const u32 CB0 = (g == 0) ? 0x00003F80u : 0u; // bf16(1.0) at k-offset 0

    f32x4 acc[8][NT];
    u32 H[NT][4][4];
    zeroacc(acc);

    __syncthreads();                                             // L0a ready
    stageA(img + IMG_L0 + 8192, &lds[1][0], 16384, wave, lane);  // L0b
    computeL0<0>(&lds[0][0], g, m, acc, xs, sc0, iscos, CB0);
    __syncthreads();                                             // L0b ready
    stageA(img + IMG_H(1), &lds[0][0], 32768, wave, lane);       // H1 slab A
    computeL0<1>(&lds[1][0], g, m, acc, xs, sc0, iscos, CB0);
    buildH(acc, H);
    __syncthreads();

#pragma unroll 1
    for (int l = 1; l < 8; l++) {
        const int ibase = IMG_H(l);
        stageA(img + ibase + 16384, &lds[1][0], 32768, wave, lane);  // slab B
        zeroacc(acc);
        computeHalf0(&lds[0][0], g, m, acc, H);
        __syncthreads();
        const u16* nsrc = (l < 7) ? (img + ibase + 32768) : (img + IMG_OUT);
        stageA(nsrc, &lds[0][0], (l < 7) ? 32768 : 8192, wave, lane);
        computeHalf1(&lds[1][0], g, m, acc, xs, sc0, iscos, CB0);
        buildH(acc, H);
        __syncthreads();
    }

    // ---- output layer: 16-row tile (4 real outputs), K=256 from slot 0 ----
    f32x4 o[NT];
#pragma unroll
    for (int n = 0; n < NT; n++) o[n] = f32x4{0.f, 0.f, 0.f, 0.f};
#pragma unroll
    for (int s = 0; s < 8; s++) {
        bf16x8 B[NT];
        if (s < 4) {
#pragma unroll
            for (int n = 0; n < NT; n++) B[n] = fr4(H[n][s]);
        } else if (s < 7) {
#pragma unroll
            for (int n = 0; n < NT; n++) B[n] = encFrag(xs[n][s - 4], sc0, iscos);
        } else {
            bf16x8 cb = frCB(CB0);
#pragma unroll
            for (int n = 0; n < NT; n++) B[n] = cb;
        }
        bf16x8 a = ldA(&lds[0][0], (4 * s + g) * 16 + m);
#pragma unroll
        for (int n = 0; n < NT; n++) o[n] = MF(a, B[n], o[n]);
    }
    if (g == 0) {
#pragma unroll
        for (int n = 0; n < NT; n++)
            *(f32x4*)(out + 4 * (pbase + n * 16 + m)) = o[n];
    }
}

// ---------------------------------------------------------------------------
extern "C" void kernel_launch(void* const* d_in, const int* in_sizes, int n_in,
                              void* d_out, int out_size, void* d_ws, size_t ws_size,
                              hipStream_t stream) {
    const float* qp = (const float*)d_in[0];
    const float* W0 = (const float*)d_in[1];
    const float* b0 = (const float*)d_in[2];
    const float* Wh = (const float*)d_in[3];
    const float* bh = (const float*)d_in[4];
    const float* Wl = (const float*)d_in[5];
    const float* bl = (const float*)d_in[6];
    float* out = (float*)d_out;
    u16* img = (u16*)d_ws;   // 499,712 B needed

    nf_prep<<<976, 256, 0, stream>>>(W0, b0, Wh, bh, Wl, bl, img);
    nf_main<<<2048, 256, 0, stream>>>(qp, img, out);
}

// Round 3
// 262.292 us; speedup vs baseline: 1.1775x; 1.0182x over previous
//
#include <hip/hip_runtime.h>
#include <stdint.h>

typedef unsigned short u16;
typedef __bf16 bf16x8 __attribute__((ext_vector_type(8)));
typedef float f32x4 __attribute__((ext_vector_type(4)));
typedef float f32x16 __attribute__((ext_vector_type(16)));
typedef unsigned int u32;

// ---------------------------------------------------------------------------
// Weight "A-image" (u16 elems), 32x32x16-MFMA A-frag native granules:
//   elem[((koct*R + row)*8) + (k&7)],  koct = k>>3, R = rows.
//   L0    : kocts 0..13 (K=112: 96 enc + bias@96 + pad), R=128 -> 14336 elems
//   Hidden: kocts 0..29 (K=240: 128 hid + 96 enc + bias@224 + pad), R=128 -> 30720
//   Out   : kocts 0..29, R=32 (4 real rows) -> 7680
// ---------------------------------------------------------------------------
#define IMG_H(l) (14336 + ((l)-1) * 30720)
#define IMG_OUT 229376
#define IMG_TOTAL 237056

// hidden-feature k-position -> producing layer's C/D feature index.
// B-frag (32x32x16): k = 16s + 8h + j (h=lane>>5, j=0..7)
// C/D: feature = 32t + (r&3) + 8*(r>>2) + 4h with s=2t+(r>>3), j=r&7
__device__ inline int fmap(int k) {
    int s = k >> 4, h = (k >> 3) & 1, j = k & 7;
    return 32 * (s >> 1) + 16 * (s & 1) + 8 * (j >> 2) + 4 * h + (j & 3);
}
__device__ inline u16 b16rne(float v) {
    u32 u = __builtin_bit_cast(u32, v);
    u += 0x7FFFu + ((u >> 16) & 1u);
    return (u16)(u >> 16);
}

// ---------------------------------------------------------------------------
// Prep kernel: build bf16 A-image (fmap-permuted hidden cols, identity enc
// cols, bias folded at k=96/224, zero padding).
// ---------------------------------------------------------------------------
__global__ void nf_prep(const float* __restrict__ W0, const float* __restrict__ b0,
                        const float* __restrict__ Wh, const float* __restrict__ bh,
                        const float* __restrict__ Wl, const float* __restrict__ bl,
                        u16* __restrict__ img) {
    int idx = blockIdx.x * 256 + threadIdx.x;
    if (idx >= IMG_TOTAL) return;
    float v;
    if (idx < 14336) {                                    // layer 0
        int gg = idx >> 3, j = idx & 7;
        int koct = gg >> 7, i = gg & 127, k = koct * 8 + j;
        v = (k < 96) ? W0[k * 128 + i] : (k == 96) ? b0[i] : 0.f;
    } else if (idx < IMG_OUT) {                           // hidden 1..7
        int r = idx - 14336, l = r / 30720, rr = r % 30720;
        int gg = rr >> 3, j = rr & 7;
        int koct = gg >> 7, i = gg & 127, k = koct * 8 + j;
        const float* W = Wh + l * 224 * 128;
        v = (k < 128) ? W[fmap(k) * 128 + i]
          : (k < 224) ? W[k * 128 + i]
          : (k == 224) ? bh[l * 128 + i] : 0.f;
    } else {                                              // output layer
        int r = idx - IMG_OUT;
        int gg = r >> 3, j = r & 7;
        int koct = gg >> 5, i = gg & 31, k = koct * 8 + j;
        v = 0.f;
        if (i < 4)
            v = (k < 128) ? Wl[fmap(k) * 4 + i]
              : (k < 224) ? Wl[k * 4 + i]
              : (k == 224) ? bl[i] : 0.f;
    }
    img[idx & 7 ? idx : idx] = 0;  // placeholder overwritten below (keep stores single)
    // recompute destination exactly as idx (layout already idx-ordered)
    img[idx] = b16rne(v);
}

// ---------------------------------------------------------------------------
// Main kernel helpers
// ---------------------------------------------------------------------------
__device__ inline f32x16 MF32(bf16x8 a, bf16x8 b, f32x16 c) {
    return __builtin_amdgcn_mfma_f32_32x32x16_bf16(a, b, c, 0, 0, 0);
}
__device__ inline bf16x8 fr4(const u32 (&p)[4]) {
    union { u32 u[4]; bf16x8 v; } x;
    x.u[0] = p[0]; x.u[1] = p[1]; x.u[2] = p[2]; x.u[3] = p[3];
    return x.v;
}
__device__ inline bf16x8 frCB(u32 c0) {
    union { u32 u[4]; bf16x8 v; } x;
    x.u[0] = c0; x.u[1] = 0; x.u[2] = 0; x.u[3] = 0;
    return x.v;
}
__device__ inline bf16x8 ldA(const u16* base, int gi) {   // ds_read_b128
    union { uint4 q; bf16x8 v; } x;
    x.q = *(const uint4*)(base + (gi << 3));
    return x.v;
}
__device__ inline u32 pkbf(float a, float b) {            // a->low, b->high
    u32 ua = __builtin_bit_cast(u32, a) + 0x8000u;
    u32 ub = __builtin_bit_cast(u32, b) + 0x8000u;
    return __builtin_amdgcn_perm(ub, ua, 0x07060302u);
}
// async global->LDS stage, 16B/lane, 1KB chunks round-robined over 4 waves
__device__ inline void stageA(const u16* gsrc, u16* ldst, int bytes, int wave, int lane) {
    const char* gs = (const char*)gsrc + lane * 16;
    char* ls = (char*)ldst;
    for (int c = wave * 1024; c < bytes; c += 4096)
        __builtin_amdgcn_global_load_lds(
            (const __attribute__((address_space(1))) void*)(gs + c),
            (__attribute__((address_space(3))) void*)(ls + c), 16, 0, 0);
}
__device__ inline void zeroacc(f32x16 (&acc)[4][2]) {
#pragma unroll
    for (int t = 0; t < 4; t++)
#pragma unroll
        for (int n = 0; n < 2; n++)
#pragma unroll
            for (int r = 0; r < 16; r++) acc[t][n][r] = 0.f;
}
// ReLU + pack accumulators into next-layer B fragments (in-register handoff)
__device__ inline void buildH(const f32x16 (&acc)[4][2], u32 (&H)[2][8][4]) {
#pragma unroll
    for (int n = 0; n < 2; n++)
#pragma unroll
        for (int s = 0; s < 8; s++) {
            const int t = s >> 1, rb = (s & 1) * 8;
#pragma unroll
            for (int q = 0; q < 4; q++)
                H[n][s][q] = pkbf(fmaxf(acc[t][n][rb + 2 * q], 0.f),
                                  fmaxf(acc[t][n][rb + 2 * q + 1], 0.f));
        }
}
// hidden half0: ksteps 0..7 (H section), slab A
__device__ inline void cHid0(const u16* A, int h, int m32, f32x16 (&acc)[4][2],
                             const u32 (&H)[2][8][4]) {
#pragma unroll
    for (int s = 0; s < 8; s++) {
        bf16x8 B0 = fr4(H[0][s]), B1 = fr4(H[1][s]);
#pragma unroll
        for (int t = 0; t < 4; t++) {
            bf16x8 a = ldA(A, (2 * s + h) * 128 + t * 32 + m32);
            acc[t][0] = MF32(a, B0, acc[t][0]);
            acc[t][1] = MF32(a, B1, acc[t][1]);
        }
    }
}
// hidden half1: local ksteps 0..6 (enc + bias), slab B
__device__ inline void cHid1(const u16* A, int h, int m32, f32x16 (&acc)[4][2],
                             const u32 (&E)[2][3][2][4], u32 CB0) {
#pragma unroll
    for (int s = 0; s < 7; s++) {
        bf16x8 B0, B1;
        if (s < 6) { B0 = fr4(E[0][s >> 1][s & 1]); B1 = fr4(E[1][s >> 1][s & 1]); }
        else       { B0 = frCB(CB0); B1 = B0; }
#pragma unroll
        for (int t = 0; t < 4; t++) {
            bf16x8 a = ldA(A, (2 * s + h) * 128 + t * 32 + m32);
            acc[t][0] = MF32(a, B0, acc[t][0]);
            acc[t][1] = MF32(a, B1, acc[t][1]);
        }
    }
}

// ---------------------------------------------------------------------------
// Main fused-MLP kernel.  Block = 256 threads = 4 waves, 256 points/block.
// Wave: 64 points (2 n-tiles of 32), all 128 features (4 m-tiles of 32).
// 32x32x16 MFMA; activations + encoding fragments live in registers;
// weights half-layer double-buffered through 2x32KB LDS slabs.
// ---------------------------------------------------------------------------
__global__ __launch_bounds__(256, 2) void nf_main(const float* __restrict__ qp,
                                                  const u16* __restrict__ img,
                                                  float* __restrict__ out) {
    __shared__ alignas(16) u16 lds[2][16384];
    const int tid = threadIdx.x, wave = tid >> 6, lane = tid & 63;
    const int m32 = lane & 31, h = lane >> 5;
    const int pbase = blockIdx.x * 256 + wave * 64;

    stageA(img, &lds[0][0], 16384, wave, lane);            // L0 kocts 0..7

    // ---- encoding fragments, computed ONCE, kept in registers ----
    // kstep (coord c, trig p): lane value j -> trig_p(x_c * 2^(8h+j) * pi)
    u32 E[2][3][2][4];
    const float sc0 = h ? 128.0f : 0.5f;                   // 2^(8h-1) revolutions
#pragma unroll
    for (int n = 0; n < 2; n++)
#pragma unroll
        for (int c = 0; c < 3; c++) {
            float r = qp[(pbase + n * 32 + m32) * 3 + c] * sc0;
            float sn[8], cs[8];
#pragma unroll
            for (int t = 0; t < 8; t++) {
                float fr = __builtin_amdgcn_fractf(r);
                sn[t] = __builtin_amdgcn_sinf(fr);
                cs[t] = __builtin_amdgcn_cosf(fr);
                r = r * 2.0f;
            }
#pragma unroll
            for (int q = 0; q < 4; q++) {
                E[n][c][0][q] = pkbf(sn[2 * q], sn[2 * q + 1]);
                E[n][c][1][q] = pkbf(cs[2 * q], cs[2 * q + 1]);
            }
        }
    const u32 CB0 = (h == 0) ? 0x00003F80u : 0u;           // bf16(1.0) at j=0,h=0

    f32x16 acc[4][2];
    u32 H[2][8][4];
    zeroacc(acc);

    __syncthreads();                                       // L0a ready
    stageA(img + 8192, &lds[1][0], 12288, wave, lane);     // L0 kocts 8..13
    // L0 half0: ksteps 0..3 (enc c=0,1)
#pragma unroll
    for (int s = 0; s < 4; s++) {
        bf16x8 B0 = fr4(E[0][s >> 1][s & 1]), B1 = fr4(E[1][s >> 1][s & 1]);
#pragma unroll
        for (int t = 0; t < 4; t++) {
            bf16x8 a = ldA(&lds[0][0], (2 * s + h) * 128 + t * 32 + m32);
            acc[t][0] = MF32(a, B0, acc[t][0]);
            acc[t][1] = MF32(a, B1, acc[t][1]);
        }
    }
    __syncthreads();                                       // L0b ready
    stageA(img + IMG_H(1), &lds[0][0], 32768, wave, lane); // H1 slab A
    // L0 half1: local ksteps 0..2 (enc c=2, bias)
#pragma unroll
    for (int s = 0; s < 3; s++) {
        bf16x8 B0, B1;
        if (s < 2) { B0 = fr4(E[0][2][s]); B1 = fr4(E[1][2][s]); }
        else       { B0 = frCB(CB0); B1 = B0; }
#pragma unroll
        for (int t = 0; t < 4; t++) {
            bf16x8 a = ldA(&lds[1][0], (2 * s + h) * 128 + t * 32 + m32);
            acc[t][0] = MF32(a, B0, acc[t][0]);
            acc[t][1] = MF32(a, B1, acc[t][1]);
        }
    }
    buildH(acc, H);
    __syncthreads();

#pragma unroll 1
    for (int l = 1; l < 8; l++) {
        const int base = IMG_H(l);
        stageA(img + base + 16384, &lds[1][0], 28672, wave, lane);  // slab B
        zeroacc(acc);
        cHid0(&lds[0][0], h, m32, acc, H);
        __syncthreads();
        const u16* nsrc = (l < 7) ? (img + base + 30720) : (img + IMG_OUT);
        stageA(nsrc, &lds[0][0], (l < 7) ? 32768 : 15360, wave, lane);
        cHid1(&lds[1][0], h, m32, acc, E, CB0);
        buildH(acc, H);
        __syncthreads();
    }

    // ---- output layer: one 32-row m-tile (rows 0..3 real), K=240, slab 0 ----
    f32x16 o0, o1;
#pragma unroll
    for (int r = 0; r < 16; r++) { o0[r] = 0.f; o1[r] = 0.f; }
#pragma unroll
    for (int s = 0; s < 15; s++) {
        bf16x8 B0, B1;
        if (s < 8)       { B0 = fr4(H[0][s]); B1 = fr4(H[1][s]); }
        else if (s < 14) { B0 = fr4(E[0][(s - 8) >> 1][(s - 8) & 1]);
                           B1 = fr4(E[1][(s - 8) >> 1][(s - 8) & 1]); }
        else             { B0 = frCB(CB0); B1 = B0; }
        bf16x8 a = ldA(&lds[0][0], (2 * s + h) * 32 + m32);
        o0 = MF32(a, B0, o0);
        o1 = MF32(a, B1, o1);
    }
    if (h == 0) {   // rows 0..3 live in regs 0..3 of the h=0 half
        f32x4 w0 = {o0[0], o0[1], o0[2], o0[3]};
        f32x4 w1 = {o1[0], o1[1], o1[2], o1[3]};
        *(f32x4*)(out + 4 * (pbase + m32)) = w0;
        *(f32x4*)(out + 4 * (pbase + 32 + m32)) = w1;
    }
}

// ---------------------------------------------------------------------------
extern "C" void kernel_launch(void* const* d_in, const int* in_sizes, int n_in,
                              void* d_out, int out_size, void* d_ws, size_t ws_size,
                              hipStream_t stream) {
    const float* qp = (const float*)d_in[0];
    const float* W0 = (const float*)d_in[1];
    const float* b0 = (const float*)d_in[2];
    const float* Wh = (const float*)d_in[3];
    const float* bh = (const float*)d_in[4];
    const float* Wl = (const float*)d_in[5];
    const float* bl = (const float*)d_in[6];
    float* out = (float*)d_out;
    u16* img = (u16*)d_ws;   // 474,112 B needed

    nf_prep<<<926, 256, 0, stream>>>(W0, b0, Wh, bh, Wl, bl, img);
    nf_main<<<2048, 256, 0, stream>>>(qp, img, out);
}